// Round 15
// baseline (304.273 us; speedup 1.0000x reference)
//
#include <hip/hip_runtime.h>
#include <hip/hip_bf16.h>
#include <stdint.h>

#define HID 2048
#define NH 32
#define NKV 8
#define HD 64
#define BSZ 2
#define SEQ 2048
#define NROWS (BSZ*SEQ)     // 4096
#define KVCOLS (NKV*HD)     // 512
#define QKVN 3072           // fused QKV output columns

typedef __attribute__((ext_vector_type(8))) short bf16x8;
typedef __attribute__((ext_vector_type(4))) float f32x4;
typedef __attribute__((ext_vector_type(16))) float f32x16;
typedef __attribute__((ext_vector_type(2))) unsigned int u32x2;

__device__ __forceinline__ unsigned short f2bf(float f) {
  union { float f; uint32_t u; } v; v.f = f;
  uint32_t r = v.u + 0x7FFFu + ((v.u >> 16) & 1u);
  return (unsigned short)(r >> 16);
}

__device__ __forceinline__ unsigned pack_bf16(float a, float b) {
  union { __hip_bfloat162 h; unsigned u; } cv;
  cv.h = __float22bfloat162_rn(make_float2(a, b));   // low 16 = a, high 16 = b
  return cv.u;
}

// balanced-tree sum of 16 floats
__device__ __forceinline__ float sum16(const f32x16& s) {
  float a0 = s[0] + s[1], a1 = s[2] + s[3], a2 = s[4] + s[5], a3 = s[6] + s[7];
  float a4 = s[8] + s[9], a5 = s[10] + s[11], a6 = s[12] + s[13], a7 = s[14] + s[15];
  float b0 = a0 + a1, b1 = a2 + a3, b2 = a4 + a5, b3 = a6 + a7;
  return (b0 + b1) + (b2 + b3);
}

// P-fragment builder: 4 cvt_pk + 2 permlane32_swap -> one bf16x8 B-fragment
#define MKPB(S, B0) ({ \
  unsigned A_ = pack_bf16((S)[B0], (S)[(B0)+1]); \
  unsigned C_ = pack_bf16((S)[(B0)+2], (S)[(B0)+3]); \
  unsigned B_ = pack_bf16((S)[(B0)+4], (S)[(B0)+5]); \
  unsigned D_ = pack_bf16((S)[(B0)+6], (S)[(B0)+7]); \
  u32x2 r0_ = __builtin_amdgcn_permlane32_swap(A_, B_, false, false); \
  u32x2 r1_ = __builtin_amdgcn_permlane32_swap(C_, D_, false, false); \
  union { uint4 u; bf16x8 v; } cv_; \
  cv_.u.x = r0_.x; cv_.u.y = r1_.x; cv_.u.z = r0_.y; cv_.u.w = r1_.y; \
  cv_.v; })

#define ROPE_C (-0.41524101186092029f)      // -ln(10000)/ln(2)/32
#define QSCL 0.18033688011112042f           // 0.125 * log2(e)

#define GLOAD(src, dst) __builtin_amdgcn_global_load_lds( \
    (const __attribute__((address_space(1))) void*)(src), \
    (__attribute__((address_space(3))) void*)(dst), 16, 0, 0)

// ---------------- merged fp32 -> bf16 convert + RoPE trig table build ----------------
#define C0 2097152
#define C1 3145728
#define C2 3407872
#define C3 3670016
#define CT 4718592
#define CT2 (CT + 32768)
__global__ __launch_bounds__(256) void cvt_all(
    const float* __restrict__ hs, const float* __restrict__ wq,
    const float* __restrict__ wk, const float* __restrict__ wv,
    const float* __restrict__ wo, const int* __restrict__ pos_ids,
    unsigned short* __restrict__ xb, unsigned short* __restrict__ wqkv,
    unsigned short* __restrict__ wob, float2* __restrict__ tab) {
  int i4 = blockIdx.x * 256 + threadIdx.x;
  const int stride = gridDim.x * 256;
  for (; i4 < CT2; i4 += stride) {
    if (i4 >= CT) {
      const int idx = i4 - CT;                 // [0, 32768)
      const int row = idx >> 3, jb = (idx & 7) * 4;
      const float pos = (float)pos_ids[row];
      float2 e[4];
      #pragma unroll
      for (int jj = 0; jj < 4; ++jj) {
        float sn, cs;
        __sincosf(pos * exp2f((float)(jb + jj) * ROPE_C), &sn, &cs);
        e[jj].x = cs; e[jj].y = sn;
      }
      *(float4*)(tab + (size_t)row * 32 + jb)     = *(const float4*)&e[0];
      *(float4*)(tab + (size_t)row * 32 + jb + 2) = *(const float4*)&e[2];
      continue;
    }
    const float* src; unsigned short* dst;
    if (i4 < C0)      { src = hs + (size_t)i4 * 4;            dst = xb   + (size_t)i4 * 4; }
    else if (i4 < C1) { src = wq + (size_t)(i4 - C0) * 4;     dst = wqkv + (size_t)(i4 - C0) * 4; }
    else if (i4 < C2) { src = wk + (size_t)(i4 - C1) * 4;     dst = wqkv + 4194304 + (size_t)(i4 - C1) * 4; }
    else if (i4 < C3) { src = wv + (size_t)(i4 - C2) * 4;     dst = wqkv + 5242880 + (size_t)(i4 - C2) * 4; }
    else              { src = wo + (size_t)(i4 - C3) * 4;     dst = wob  + (size_t)(i4 - C3) * 4; }
    float4 v = *(const float4*)src;
    ushort4 o;
    o.x = f2bf(v.x); o.y = f2bf(v.y); o.z = f2bf(v.z); o.w = f2bf(v.w);
    *(ushort4*)dst = o;
  }
}

// ================= 256x256 deep-pipelined GEMM core (BK=64, 8 waves, 128KB LDS) =============
// LDS per buf (64KB): A-half0 @0, A-half1 @16384, B-half0 @32768, B-half1 @49152.
// Halves are M/N row-blocks of 128 x [64 k] bf16 = 128B rows, XOR-swizzled
// col ^ ((row&7)<<4) via pre-swizzled global_load_lds sources (rule 21).
// Wave w: wr=w>>2 (M-half), wcn=w&3 (64-col strip). Each wave stages ONLY slices of
// its own halves; vmcnt(0)+barrier once per K-tile (loads have full-tile cover).
// Per K-tile: 4 sub-phases {ds_read, barrier, 16 MFMA, barrier} (T3 interleave + T5).
// acc[8][4]: rows wr*128+mi*16+(l>>4)*4+r, cols wcn*64+ni*16+(l&15).
#define G_STAGE8(bufB, ktn) \
  { \
    _Pragma("unroll") \
    for (int j = 0; j < 4; ++j) { \
      int d = wcn * 4096 + j * 1024 + l * 16; \
      int colp = (d & 127) ^ (((d >> 7) & 7) << 4); \
      GLOAD((const char*)A + (size_t)(row0 + wr * 128 + (d >> 7)) * 4096 + (ktn) * 128 + colp, \
            SL + (bufB) + wr * 16384 + d); \
    } \
    _Pragma("unroll") \
    for (int j = 0; j < 4; ++j) { \
      int d = (wr * 2 + (wcn & 1)) * 4096 + j * 1024 + l * 16; \
      int colp = (d & 127) ^ (((d >> 7) & 7) << 4); \
      GLOAD((const char*)B + (size_t)(col0 + (wcn >> 1) * 128 + (d >> 7)) * 4096 + (ktn) * 128 + colp, \
            SL + (bufB) + 32768 + (wcn >> 1) * 16384 + d); \
    } \
  }

#define G_TILE(bufB) \
  _Pragma("unroll") \
  for (int ks = 0; ks < 2; ++ks) { \
    bf16x8 af[8]; \
    _Pragma("unroll") \
    for (int mi = 0; mi < 8; ++mi) \
      af[mi] = *(const bf16x8*)(SL + (bufB) + ABb + mi * 2048 + laneK[ks]); \
    _Pragma("unroll") \
    for (int nh = 0; nh < 2; ++nh) { \
      bf16x8 b0 = *(const bf16x8*)(SL + (bufB) + BBb + (nh * 2) * 2048 + laneK[ks]); \
      bf16x8 b1 = *(const bf16x8*)(SL + (bufB) + BBb + (nh * 2 + 1) * 2048 + laneK[ks]); \
      __builtin_amdgcn_s_barrier(); \
      __builtin_amdgcn_sched_barrier(0); \
      __builtin_amdgcn_s_setprio(1); \
      _Pragma("unroll") \
      for (int mi = 0; mi < 8; ++mi) { \
        acc[mi][nh * 2]     = __builtin_amdgcn_mfma_f32_16x16x32_bf16(af[mi], b0, acc[mi][nh * 2], 0, 0, 0); \
        acc[mi][nh * 2 + 1] = __builtin_amdgcn_mfma_f32_16x16x32_bf16(af[mi], b1, acc[mi][nh * 2 + 1], 0, 0, 0); \
      } \
      __builtin_amdgcn_s_setprio(0); \
      __builtin_amdgcn_s_barrier(); \
      __builtin_amdgcn_sched_barrier(0); \
    } \
  }

#define G_PREAMBLE \
  __shared__ char SL[131072]; \
  const int t = threadIdx.x; \
  const int w = t >> 6, l = t & 63; \
  const int wr = w >> 2, wcn = w & 3; \
  const int lr = l & 15, lk2 = (l >> 4) * 16; \
  const int sw7 = (lr & 7) << 4; \
  const int nwg = gridDim.x * gridDim.y; \
  const int lin = blockIdx.y * gridDim.x + blockIdx.x; \
  const int swzb = (lin & 7) * (nwg >> 3) + (lin >> 3); \
  const int bx = swzb % gridDim.x, by = swzb / gridDim.x; \
  const int row0 = by * 256, col0 = bx * 256; \
  int laneK[2]; \
  laneK[0] = lr * 128 + (lk2 ^ sw7); \
  laneK[1] = lr * 128 + ((64 + lk2) ^ sw7); \
  const int ABb = wr * 16384; \
  const int BBb = 32768 + (wcn >> 1) * 16384 + (wcn & 1) * 8192; \
  f32x4 acc[8][4]; \
  _Pragma("unroll") \
  for (int i = 0; i < 8; ++i) \
    _Pragma("unroll") \
    for (int j = 0; j < 4; ++j) acc[i][j] = (f32x4){0.f, 0.f, 0.f, 0.f}; \
  G_STAGE8(0, 0); \
  asm volatile("s_waitcnt vmcnt(0)" ::: "memory"); \
  __syncthreads(); \
  _Pragma("unroll 1") \
  for (int kt2 = 0; kt2 < 16; ++kt2) { \
    const int kt = kt2 * 2; \
    if (kt + 1 < 32) G_STAGE8(65536, kt + 1); \
    G_TILE(0); \
    asm volatile("s_waitcnt vmcnt(0)" ::: "memory"); \
    __builtin_amdgcn_s_barrier(); \
    __builtin_amdgcn_sched_barrier(0); \
    if (kt + 2 < 32) G_STAGE8(0, kt + 2); \
    G_TILE(65536); \
    asm volatile("s_waitcnt vmcnt(0)" ::: "memory"); \
    __builtin_amdgcn_s_barrier(); \
    __builtin_amdgcn_sched_barrier(0); \
  }

// ---------------- O-proj GEMM 256^2: C[M][2048] = A * B^T, fp32 out ----------------
__global__ __launch_bounds__(512, 2) void gemm_btn256(
    const unsigned short* __restrict__ A,
    const unsigned short* __restrict__ B,
    float* __restrict__ C)
{
  G_PREAMBLE
  const int crow = (l >> 4) * 4, ccol = l & 15;
  #pragma unroll
  for (int mi = 0; mi < 8; ++mi)
    #pragma unroll
    for (int ni = 0; ni < 4; ++ni) {
      float* cp = C + (size_t)(row0 + wr * 128 + mi * 16 + crow) * HID + col0 + wcn * 64 + ni * 16 + ccol;
      #pragma unroll
      for (int r = 0; r < 4; ++r)
        cp[(size_t)r * HID] = acc[mi][ni][r];
    }
}

// ---------------- Fused QKV GEMM 256^2: proj + RoPE(table) + layout, bf16 out ----------------
// Wave strip = 128 s-rows x one 64-col head region -> same per-wave LDS-transpose
// epilogues as before, extended to 128 rows (16KB wave-private region = SL + w*16384).
__global__ __launch_bounds__(512, 2) void gemm_qkv256(
    const unsigned short* __restrict__ A,    // Xb [4096][2048]
    const unsigned short* __restrict__ B,    // Wqkvb [3072][2048]
    const float2* __restrict__ tab,          // [NROWS][32] {cos,sin}
    unsigned short* __restrict__ Qb,         // [B][NH][SEQ][64]
    unsigned short* __restrict__ Kb,         // [B][NKV][SEQ][64]
    unsigned short* __restrict__ Vt)         // [B][NKV][64][SEQ]
{
  G_PREAMBLE
  // ---- epilogue (SL free after final tile barrier) ----
  const int crow = (l >> 4) * 4, ccol = l & 15;
  const int colbase = col0 + wcn * 64;       // 64-aligned -> strip is pure Q, K, or V
  const int b = row0 >> 11;                  // batch (256-row tile never crosses: 2048%256==0)
  const int s0row = (row0 + wr * 128) & (SEQ - 1);
  char* Tw = SL + w * 16384;                 // wave-private 16KB

  if (colbase < HID + KVCOLS) {
    // ---- Q or K: RoPE rotate via table -> LDS [sl][d] (swizzled) -> coalesced stores ----
    const bool isQ = colbase < HID;
    const float scl = isQ ? QSCL : 1.0f;
    const int hh = (isQ ? colbase : colbase - HID) >> 6;
    unsigned short* base = (isQ ? Qb + ((size_t)(b * NH + hh) * SEQ) * HD
                                : Kb + ((size_t)(b * NKV + hh) * SEQ) * HD);
    #pragma unroll
    for (int mi = 0; mi < 8; ++mi) {
      #pragma unroll
      for (int r = 0; r < 4; ++r) {
        const int sl = mi * 16 + crow + r;             // local s in [0,128)
        const int row = row0 + wr * 128 + sl;
        const int xsw = (sl & 7) << 4;
        const float2* tr = tab + (size_t)row * 32 + ccol;
        #pragma unroll
        for (int ni = 0; ni < 2; ++ni) {
          const float2 cssn = tr[ni * 16];
          const float x1 = acc[mi][ni][r], x2 = acc[mi][ni + 2][r];
          const int d1 = (ni * 16 + ccol) * 2;
          *(unsigned short*)(Tw + ((sl * 128 + d1) ^ xsw)) =
              f2bf((x1 * cssn.x - x2 * cssn.y) * scl);
          *(unsigned short*)(Tw + ((sl * 128 + d1 + 64) ^ xsw)) =
              f2bf((x2 * cssn.x + x1 * cssn.y) * scl);
        }
      }
    }
    // wave-private region (rule 18; no __syncthreads -- sibling waves may be in V branch)
    asm volatile("s_waitcnt lgkmcnt(0)" ::: "memory");
    __builtin_amdgcn_sched_barrier(0);
    const int dl = l >> 3, sg = l & 7;
    #pragma unroll
    for (int dg = 0; dg < 16; ++dg) {
      const int sl = dg * 8 + dl;
      uint4 v = *(const uint4*)(Tw + ((sl * 128 + sg * 16) ^ ((sl & 7) << 4)));
      *(uint4*)((char*)base + (size_t)(s0row + sl) * 128 + sg * 16) = v;
    }
  } else {
    // ---- V: stage [d][128 s] in wave-private LDS (XOR swizzle), coalesced 16B stores ----
    const int cv = colbase - (HID + KVCOLS);
    const int kh = cv >> 6;
    unsigned short* vbase = Vt + ((size_t)(b * NKV + kh) * HD) * SEQ;
    #pragma unroll
    for (int ni = 0; ni < 4; ++ni) {
      const int d = ni * 16 + ccol;
      #pragma unroll
      for (int mi = 0; mi < 8; ++mi) {
        const int sl = mi * 16 + crow;
        ushort4 o;
        o.x = f2bf(acc[mi][ni][0]);
        o.y = f2bf(acc[mi][ni][1]);
        o.z = f2bf(acc[mi][ni][2]);
        o.w = f2bf(acc[mi][ni][3]);
        *(ushort4*)(Tw + (d * 256 + ((sl * 2) ^ ((d & 7) << 4)))) = o;
      }
    }
    asm volatile("s_waitcnt lgkmcnt(0)" ::: "memory");
    __builtin_amdgcn_sched_barrier(0);
    const int dl2 = l >> 4, sgl = l & 15;
    #pragma unroll
    for (int dg = 0; dg < 16; ++dg) {
      const int d = dg * 4 + dl2;
      uint4 v = *(const uint4*)(Tw + (d * 256 + ((sgl * 16) ^ ((d & 7) << 4))));
      *(uint4*)(vbase + (size_t)d * SEQ + s0row + sgl * 8) = v;
    }
  }
}

// ---------------- Flash attention: R13-exact (measured 121.8us) ----------------
__global__ __launch_bounds__(512, 4) void attn_kernel(
    const unsigned short* __restrict__ Qb,   // [B][NH][SEQ][64] bf16, rope'd+scaled
    const unsigned short* __restrict__ Kb,   // [B][NKV][SEQ][64] bf16, rope'd
    const unsigned short* __restrict__ Vt,   // [B][NKV][64][SEQ] bf16
    unsigned short* __restrict__ AO)         // [B*SEQ][HID] bf16
{
  __shared__ unsigned short Ks[2][64 * 64];  // [key][d] swizzled, 8KB each
  __shared__ unsigned short Vs[2][64 * 64];  // [d][key] swizzled, 8KB each

  const int lin = blockIdx.x;
  const int bid = (lin & 7) * 64 + (lin >> 3);
  const int qtile = bid & 7;                 // SEQ/256 = 8
  const int h = (bid >> 3) & 31;
  const int b = bid >> 8;
  const int kh = h >> 2;
  const int t = threadIdx.x, w = t >> 6, l = t & 63;
  const int lq = l & 31, hi = l >> 5;
  const int sw = (lq & 7) << 4;
  const int qrow = qtile * 256 + w * 32 + lq;

  bf16x8 qf[4];
  {
    const unsigned short* Qrow = Qb + ((size_t)(b * NH + h) * SEQ + qrow) * HD;
    #pragma unroll
    for (int dk = 0; dk < 4; ++dk)
      qf[dk] = *(const bf16x8*)(Qrow + dk * 16 + hi * 8);
  }

  const unsigned short* Kt  = Kb + (size_t)(b * NKV + kh) * SEQ * HD;
  const unsigned short* Vth = Vt + (size_t)(b * NKV + kh) * HD * SEQ;

  const int dest = t * 16;
  const int srow = dest >> 7;
  const int scol = dest & 127;
  const int wdest = dest ^ ((srow & 7) << 4);
  const char* KsrcBase = (const char*)Kt + dest;
  const char* VsrcBase = (const char*)(Vth + (size_t)srow * SEQ) + scol;

  uint4 kreg, vreg;
  auto issue = [&](int kv0) {
    kreg = *(const uint4*)(KsrcBase + (size_t)kv0 * 128);
    vreg = *(const uint4*)(VsrcBase + kv0 * 2);
  };
  auto lwrite = [&](int si) {
    *(uint4*)((char*)Ks[si] + wdest) = kreg;
    *(uint4*)((char*)Vs[si] + wdest) = vreg;
  };

  const f32x16 Z = {0,0,0,0,0,0,0,0,0,0,0,0,0,0,0,0};
  float lsum = 0.f;
  f32x16 o0 = Z, o1 = Z;

  issue(0);
  lwrite(0);
  __syncthreads();

  int bi = 0;
  for (int it = 0; it < SEQ / 64; ++it) {
    const bool more = (it + 1 < SEQ / 64);
    if (more) issue((it + 1) * 64);

    const char* Kp = (const char*)Ks[bi];
    const char* Vp = (const char*)Vs[bi];

    f32x16 s0, s1;
    __builtin_amdgcn_s_setprio(1);
    {
      bf16x8 kf0 = *(const bf16x8*)(Kp + lq * 128 + ((hi * 16) ^ sw));
      bf16x8 kf1 = *(const bf16x8*)(Kp + 4096 + lq * 128 + ((hi * 16) ^ sw));
      s0 = __builtin_amdgcn_mfma_f32_32x32x16_bf16(kf0, qf[0], Z, 0, 0, 0);
      s1 = __builtin_amdgcn_mfma_f32_32x32x16_bf16(kf1, qf[0], Z, 0, 0, 0);
    }
    #pragma unroll
    for (int dk = 1; dk < 4; ++dk) {
      const int cb = dk * 32 + hi * 16;
      bf16x8 kf0 = *(const bf16x8*)(Kp + lq * 128 + (cb ^ sw));
      bf16x8 kf1 = *(const bf16x8*)(Kp + 4096 + lq * 128 + (cb ^ sw));
      s0 = __builtin_amdgcn_mfma_f32_32x32x16_bf16(kf0, qf[dk], s0, 0, 0, 0);
      s1 = __builtin_amdgcn_mfma_f32_32x32x16_bf16(kf1, qf[dk], s1, 0, 0, 0);
    }
    __builtin_amdgcn_s_setprio(0);

    #pragma unroll
    for (int r = 0; r < 16; ++r) { s0[r] = exp2f(s0[r]); s1[r] = exp2f(s1[r]); }
    float rs = sum16(s0) + sum16(s1);
    rs += __shfl_xor(rs, 32);
    lsum += rs;

    bf16x8 pb0 = MKPB(s0, 0), pb1 = MKPB(s0, 8), pb2 = MKPB(s1, 0), pb3 = MKPB(s1, 8);

    __builtin_amdgcn_s_setprio(1);
    #pragma unroll
    for (int ks = 0; ks < 4; ++ks) {
      const int cb = ks * 32 + hi * 16;
      bf16x8 vf0 = *(const bf16x8*)(Vp + lq * 128 + (cb ^ sw));
      bf16x8 vf1 = *(const bf16x8*)(Vp + 4096 + lq * 128 + (cb ^ sw));
      bf16x8 pa = (ks == 0) ? pb0 : (ks == 1) ? pb1 : (ks == 2) ? pb2 : pb3;
      o0 = __builtin_amdgcn_mfma_f32_32x32x16_bf16(vf0, pa, o0, 0, 0, 0);
      o1 = __builtin_amdgcn_mfma_f32_32x32x16_bf16(vf1, pa, o1, 0, 0, 0);
    }
    __builtin_amdgcn_s_setprio(0);

    if (more) lwrite(bi ^ 1);
    __syncthreads();
    bi ^= 1;
  }

  const float inv = 1.0f / lsum;
  unsigned short* op = AO + ((size_t)(b * SEQ) + qrow) * HID + h * 64;
  #pragma unroll
  for (int r = 0; r < 16; r += 2) {
    const int d = (r & 3) + 8 * (r >> 2) + 4 * hi;
    *(unsigned*)(op + d)      = pack_bf16(o0[r] * inv, o0[r + 1] * inv);
    *(unsigned*)(op + 32 + d) = pack_bf16(o1[r] * inv, o1[r + 1] * inv);
  }
}

// ---------------- launch ----------------
extern "C" void kernel_launch(void* const* d_in, const int* in_sizes, int n_in,
                              void* d_out, int out_size, void* d_ws, size_t ws_size,
                              hipStream_t stream) {
  const float* hs  = (const float*)d_in[0];
  const int*   pos = (const int*)d_in[1];
  const float* Wq  = (const float*)d_in[2];
  const float* Wk  = (const float*)d_in[3];
  const float* Wv  = (const float*)d_in[4];
  const float* Wo  = (const float*)d_in[5];
  float* out = (float*)d_out;

  char* ws = (char*)d_ws;
  size_t off = 0;
  auto carve = [&](size_t bytes) { void* p = ws + off; off += (bytes + 255) & ~(size_t)255; return p; };

  unsigned short* Xb    = (unsigned short*)carve((size_t)NROWS * HID * 2);
  unsigned short* Wqkvb = (unsigned short*)carve((size_t)QKVN * HID * 2);   // [Wq;Wk;Wv] rows
  unsigned short* Wob   = (unsigned short*)carve((size_t)HID * HID * 2);
  unsigned short* Qbh   = (unsigned short*)carve((size_t)NROWS * HID * 2);
  unsigned short* Kbh   = (unsigned short*)carve((size_t)NROWS * KVCOLS * 2);
  unsigned short* Vtb   = (unsigned short*)carve((size_t)NROWS * KVCOLS * 2);
  unsigned short* AO    = (unsigned short*)carve((size_t)NROWS * HID * 2);
  float2*         Tab   = (float2*)carve((size_t)NROWS * 32 * sizeof(float2));

  // all fp32->bf16 converts + trig table in one launch
  cvt_all<<<2048, 256, 0, stream>>>(hs, Wq, Wk, Wv, Wo, pos, Xb, Wqkvb, Wob, Tab);

  // fused QKV projection + RoPE(table) + layout: 256^2 tiles, 192 blocks (%8==0)
  gemm_qkv256<<<dim3(QKVN / 256, NROWS / 256), 512, 0, stream>>>(Xb, Wqkvb, Tab, Qbh, Kbh, Vtb);

  // attention: 512 blocks x 8 waves, 256 q-rows each
  attn_kernel<<<BSZ * NH * (SEQ / 256), 512, 0, stream>>>(Qbh, Kbh, Vtb, AO);

  // output projection: 256^2 tiles, 128 blocks (%8==0)
  gemm_btn256<<<dim3(HID / 256, NROWS / 256), 512, 0, stream>>>(AO, Wob, out);
}